// Round 2
// baseline (287.200 us; speedup 1.0000x reference)
//
#include <hip/hip_runtime.h>
#include <hip/hip_bf16.h>
#include <stdint.h>

#define N_TOK 2048
#define C_IN 256
#define HEADS 8
#define DH 32
#define HDIM 256
#define LOG2E 1.4426950408889634f

typedef __attribute__((ext_vector_type(8))) short short8;
typedef __attribute__((ext_vector_type(4))) float float4_t;

__device__ __forceinline__ short f2b(float f) {
    unsigned u = __builtin_bit_cast(unsigned, f);
    unsigned r = (u + 0x7FFFu + ((u >> 16) & 1u)) >> 16;
    return (short)(r & 0xFFFFu);
}

// ---------------- prep: f32 -> bf16 conversions ----------------
__global__ void prep_x(const float* __restrict__ qx, const float* __restrict__ kvx,
                       short* __restrict__ Xq, short* __restrict__ Xkv) {
    int idx = blockIdx.x * blockDim.x + threadIdx.x;
    int base = idx * 8;
    const int NX = N_TOK * C_IN;
    const float* src; short* dst; int off;
    if (base < NX) { src = qx;  dst = Xq;  off = base; }
    else           { src = kvx; dst = Xkv; off = base - NX; }
    float4_t a = *(const float4_t*)(src + off);
    float4_t b = *(const float4_t*)(src + off + 4);
    short8 o;
    o[0] = f2b(a[0]); o[1] = f2b(a[1]); o[2] = f2b(a[2]); o[3] = f2b(a[3]);
    o[4] = f2b(b[0]); o[5] = f2b(b[1]); o[6] = f2b(b[2]); o[7] = f2b(b[3]);
    *(short8*)(dst + off) = o;
}

// transpose+convert the 5 weight matrices: Wt[j][c] = bf16(W[c][j])
__global__ void prep_w(const float* __restrict__ Wq, const float* __restrict__ Wk,
                       const float* __restrict__ Wv, const float* __restrict__ Wg,
                       const float* __restrict__ Wo,
                       short* __restrict__ Wtq, short* __restrict__ Wtk,
                       short* __restrict__ Wtv, short* __restrict__ Wtg,
                       short* __restrict__ Wto) {
    int wi = blockIdx.y;
    int j = blockIdx.x;
    int c = threadIdx.x;
    const float* W; short* Wt;
    switch (wi) {
        case 0: W = Wq; Wt = Wtq; break;
        case 1: W = Wk; Wt = Wtk; break;
        case 2: W = Wv; Wt = Wtv; break;
        case 3: W = Wg; Wt = Wtg; break;
        default: W = Wo; Wt = Wto; break;
    }
    Wt[j * 256 + c] = f2b(W[c * 256 + j]);
}

// ---------------- projections ----------------
// out[n][col] = sum_c X[n][c] * Wt[col][c]; modes: 0=q(scaled,bf16 head-major),
// 1=k(bf16 head-major), 2=gate(sigmoid, f32 [n][256])
__global__ void proj_nh(const short* __restrict__ Xq, const short* __restrict__ Xkv,
                        const short* __restrict__ Wtq, const short* __restrict__ Wtk,
                        const short* __restrict__ Wtg, const float* __restrict__ bg,
                        short* __restrict__ qh, short* __restrict__ kh,
                        float* __restrict__ gsig) {
    int tid = threadIdx.x, wave = tid >> 6, lane = tid & 63, g16 = lane >> 4, li = lane & 15;
    int mode = blockIdx.z;
    const short* X  = (mode == 1) ? Xkv : Xq;
    const short* Wt = (mode == 0) ? Wtq : (mode == 1 ? Wtk : Wtg);
    int n0 = blockIdx.x * 64 + wave * 16;
    int c0 = blockIdx.y * 64;
    float4_t acc[4];
#pragma unroll
    for (int j = 0; j < 4; j++) acc[j] = (float4_t){0.f, 0.f, 0.f, 0.f};
    for (int k0 = 0; k0 < C_IN; k0 += 32) {
        short8 a = *(const short8*)(X + (n0 + li) * C_IN + k0 + g16 * 8);
#pragma unroll
        for (int j = 0; j < 4; j++) {
            short8 b = *(const short8*)(Wt + (c0 + j * 16 + li) * C_IN + k0 + g16 * 8);
            acc[j] = __builtin_amdgcn_mfma_f32_16x16x32_bf16(a, b, acc[j], 0, 0, 0);
        }
    }
#pragma unroll
    for (int j = 0; j < 4; j++) {
#pragma unroll
        for (int r = 0; r < 4; r++) {
            int n = n0 + g16 * 4 + r;
            int col = c0 + j * 16 + li;
            float v = acc[j][r];
            if (mode == 0) {
                qh[(col >> 5) * (N_TOK * DH) + n * DH + (col & 31)] =
                    f2b(v * 0.17677669529663687f);  // 1/sqrt(32)
            } else if (mode == 1) {
                kh[(col >> 5) * (N_TOK * DH) + n * DH + (col & 31)] = f2b(v);
            } else {
                float x = v + bg[col];
                gsig[n * HDIM + col] = 1.f / (1.f + __expf(-x));
            }
        }
    }
}

// Vt[hd][n] = sum_c Wtv[hd][c] * Xkv[n][c]  (V pre-transposed per head)
__global__ void proj_hn(const short* __restrict__ Xkv, const short* __restrict__ Wtv,
                        short* __restrict__ vt) {
    int tid = threadIdx.x, wave = tid >> 6, lane = tid & 63, g16 = lane >> 4, li = lane & 15;
    int hd0 = blockIdx.x * 64 + wave * 16;
    int n0 = blockIdx.y * 64;
    float4_t acc[4];
#pragma unroll
    for (int j = 0; j < 4; j++) acc[j] = (float4_t){0.f, 0.f, 0.f, 0.f};
    for (int k0 = 0; k0 < C_IN; k0 += 32) {
        short8 a = *(const short8*)(Wtv + (hd0 + li) * C_IN + k0 + g16 * 8);
#pragma unroll
        for (int j = 0; j < 4; j++) {
            short8 b = *(const short8*)(Xkv + (n0 + j * 16 + li) * C_IN + k0 + g16 * 8);
            acc[j] = __builtin_amdgcn_mfma_f32_16x16x32_bf16(a, b, acc[j], 0, 0, 0);
        }
    }
#pragma unroll
    for (int j = 0; j < 4; j++) {
#pragma unroll
        for (int r = 0; r < 4; r++) {
            int hd = hd0 + g16 * 4 + r;
            int n = n0 + j * 16 + li;
            vt[hd * N_TOK + n] = f2b(acc[j][r]);
        }
    }
}

// ---------------- flash attention ----------------
// grid (32 qblocks, 8 heads), 256 thr. Wave w: q rows [qb*64+w*16, +16).
__global__ void attn(const short* __restrict__ qh, const short* __restrict__ kh,
                     const short* __restrict__ vt, const float* __restrict__ bias_mask,
                     const float* __restrict__ bias_pair, const float* __restrict__ gsig,
                     short* __restrict__ OG) {
    __shared__ short plds[4][16][72];  // per-wave P tile, stride 72 halves (16B-aligned rows)
    int tid = threadIdx.x, wave = tid >> 6, lane = tid & 63, g16 = lane >> 4, li = lane & 15;
    int h = blockIdx.y, qb = blockIdx.x;
    int qbase = qb * 64 + wave * 16;
    const short* qp = qh + h * (N_TOK * DH);
    const short* kp = kh + h * (N_TOK * DH);
    const short* vp = vt + h * (DH * N_TOK);
    short8 qa = *(const short8*)(qp + (qbase + li) * DH + g16 * 8);
    const float* bpp = bias_pair + (size_t)(h * N_TOK + qbase) * N_TOK;
    float m[4], l[4];
    float4_t o0 = {0.f, 0.f, 0.f, 0.f}, o1 = {0.f, 0.f, 0.f, 0.f};
#pragma unroll
    for (int r = 0; r < 4; r++) { m[r] = -1e30f; l[r] = 0.f; }
    const float4_t z4 = {0.f, 0.f, 0.f, 0.f};

    for (int kb = 0; kb < N_TOK; kb += 64) {
        float4_t s[4];
#pragma unroll
        for (int t = 0; t < 4; t++) {
            short8 kf = *(const short8*)(kp + (kb + t * 16 + li) * DH + g16 * 8);
            s[t] = __builtin_amdgcn_mfma_f32_16x16x32_bf16(qa, kf, z4, 0, 0, 0);
        }
        float bm[4];
#pragma unroll
        for (int t = 0; t < 4; t++) bm[t] = bias_mask[kb + t * 16 + li];
        float bp[4][4];
#pragma unroll
        for (int t = 0; t < 4; t++)
#pragma unroll
            for (int r = 0; r < 4; r++)
                bp[t][r] = bpp[(g16 * 4 + r) * N_TOK + kb + t * 16 + li];
        float sc[4][4];
#pragma unroll
        for (int t = 0; t < 4; t++)
#pragma unroll
            for (int r = 0; r < 4; r++) sc[t][r] = s[t][r] + bm[t] + bp[t][r];

        // online softmax per q-row (row = 4*g16 + r lives in the 16-lane group g16)
#pragma unroll
        for (int r = 0; r < 4; r++) {
            float mx = fmaxf(fmaxf(sc[0][r], sc[1][r]), fmaxf(sc[2][r], sc[3][r]));
#pragma unroll
            for (int off = 1; off < 16; off <<= 1) mx = fmaxf(mx, __shfl_xor(mx, off));
            float mn = fmaxf(m[r], mx);
            float sscale = exp2f((m[r] - mn) * LOG2E);
            float su = 0.f;
#pragma unroll
            for (int t = 0; t < 4; t++) {
                float p = exp2f((sc[t][r] - mn) * LOG2E);
                sc[t][r] = p;
                su += p;
            }
#pragma unroll
            for (int off = 1; off < 16; off <<= 1) su += __shfl_xor(su, off);
            l[r] = l[r] * sscale + su;
            m[r] = mn;
            o0[r] *= sscale;
            o1[r] *= sscale;
        }

        // P -> bf16 -> per-wave LDS tile, then read back as A-fragments
#pragma unroll
        for (int t = 0; t < 4; t++)
#pragma unroll
            for (int r = 0; r < 4; r++)
                plds[wave][g16 * 4 + r][t * 16 + li] = f2b(sc[t][r]);
        short8 pa0 = *(const short8*)&plds[wave][li][g16 * 8];
        short8 pa1 = *(const short8*)&plds[wave][li][32 + g16 * 8];

        short8 v00 = *(const short8*)(vp + li * N_TOK + kb + g16 * 8);
        short8 v01 = *(const short8*)(vp + li * N_TOK + kb + 32 + g16 * 8);
        short8 v10 = *(const short8*)(vp + (16 + li) * N_TOK + kb + g16 * 8);
        short8 v11 = *(const short8*)(vp + (16 + li) * N_TOK + kb + 32 + g16 * 8);
        o0 = __builtin_amdgcn_mfma_f32_16x16x32_bf16(pa0, v00, o0, 0, 0, 0);
        o0 = __builtin_amdgcn_mfma_f32_16x16x32_bf16(pa1, v01, o0, 0, 0, 0);
        o1 = __builtin_amdgcn_mfma_f32_16x16x32_bf16(pa0, v10, o1, 0, 0, 0);
        o1 = __builtin_amdgcn_mfma_f32_16x16x32_bf16(pa1, v11, o1, 0, 0, 0);
    }

    // epilogue: normalize, gate, store bf16 [n][256]
#pragma unroll
    for (int r = 0; r < 4; r++) {
        float inv = 1.f / l[r];
        int n = qbase + g16 * 4 + r;
        int col0 = h * DH + li;
        int col1 = h * DH + 16 + li;
        OG[n * HDIM + col0] = f2b(o0[r] * inv * gsig[n * HDIM + col0]);
        OG[n * HDIM + col1] = f2b(o1[r] * inv * gsig[n * HDIM + col1]);
    }
}

// ---------------- output projection ----------------
__global__ void outproj(const short* __restrict__ OG, const short* __restrict__ Wto,
                        const float* __restrict__ bo, float* __restrict__ out) {
    int tid = threadIdx.x, wave = tid >> 6, lane = tid & 63, g16 = lane >> 4, li = lane & 15;
    int n0 = blockIdx.x * 64 + wave * 16;
    int c0 = blockIdx.y * 64;
    float4_t acc[4];
#pragma unroll
    for (int j = 0; j < 4; j++) acc[j] = (float4_t){0.f, 0.f, 0.f, 0.f};
    for (int k0 = 0; k0 < HDIM; k0 += 32) {
        short8 a = *(const short8*)(OG + (n0 + li) * HDIM + k0 + g16 * 8);
#pragma unroll
        for (int j = 0; j < 4; j++) {
            short8 b = *(const short8*)(Wto + (c0 + j * 16 + li) * HDIM + k0 + g16 * 8);
            acc[j] = __builtin_amdgcn_mfma_f32_16x16x32_bf16(a, b, acc[j], 0, 0, 0);
        }
    }
#pragma unroll
    for (int j = 0; j < 4; j++) {
#pragma unroll
        for (int r = 0; r < 4; r++) {
            int n = n0 + g16 * 4 + r;
            int col = c0 + j * 16 + li;
            out[n * C_IN + col] = acc[j][r] + bo[col];
        }
    }
}

extern "C" void kernel_launch(void* const* d_in, const int* in_sizes, int n_in,
                              void* d_out, int out_size, void* d_ws, size_t ws_size,
                              hipStream_t stream) {
    const float* q_x       = (const float*)d_in[0];
    const float* kv_x      = (const float*)d_in[1];
    const float* bias_mask = (const float*)d_in[2];
    const float* bias_pair = (const float*)d_in[3];
    const float* Wq        = (const float*)d_in[4];
    const float* Wk        = (const float*)d_in[5];
    const float* Wv        = (const float*)d_in[6];
    const float* Wo        = (const float*)d_in[7];
    const float* bo        = (const float*)d_in[8];
    const float* Wg        = (const float*)d_in[9];
    const float* bg        = (const float*)d_in[10];
    float* out = (float*)d_out;
    char* ws = (char*)d_ws;

    short* Xq   = (short*)(ws);                    // 1 MB
    short* Xkv  = (short*)(ws + (1u << 20));       // 1 MB
    short* Wtq  = (short*)(ws + (2u << 20));       // 5 x 128 KB
    short* Wtk  = Wtq + 65536;
    short* Wtv  = Wtk + 65536;
    short* Wtg  = Wtv + 65536;
    short* Wto  = Wtg + 65536;
    short* qhb  = (short*)(ws + (3u << 20));       // 1 MB  [h][n][d] bf16
    short* khb  = (short*)(ws + (4u << 20));       // 1 MB
    short* vtb  = (short*)(ws + (5u << 20));       // 1 MB  [h][d][n] bf16
    float* gsig = (float*)(ws + (6u << 20));       // 2 MB  [n][256] f32
    short* OG   = (short*)(ws + (8u << 20));       // 1 MB  [n][256] bf16

    hipLaunchKernelGGL(prep_x, dim3(512), dim3(256), 0, stream, q_x, kv_x, Xq, Xkv);
    hipLaunchKernelGGL(prep_w, dim3(256, 5), dim3(256), 0, stream,
                       Wq, Wk, Wv, Wg, Wo, Wtq, Wtk, Wtv, Wtg, Wto);
    hipLaunchKernelGGL(proj_nh, dim3(32, 4, 3), dim3(256), 0, stream,
                       Xq, Xkv, Wtq, Wtk, Wtg, bg, qhb, khb, gsig);
    hipLaunchKernelGGL(proj_hn, dim3(4, 32), dim3(256), 0, stream, Xkv, Wtv, vtb);
    hipLaunchKernelGGL(attn, dim3(32, 8), dim3(256), 0, stream,
                       qhb, khb, vtb, bias_mask, bias_pair, gsig, OG);
    hipLaunchKernelGGL(outproj, dim3(32, 4), dim3(256), 0, stream, OG, Wto, bo, out);
}

// Round 4
// 247.244 us; speedup vs baseline: 1.1616x; 1.1616x over previous
//
#include <hip/hip_runtime.h>
#include <hip/hip_bf16.h>
#include <stdint.h>

#define N_TOK 2048
#define C_IN 256
#define HEADS 8
#define DH 32
#define HDIM 256
#define LOG2E 1.4426950408889634f

typedef __attribute__((ext_vector_type(8))) short short8;
typedef __attribute__((ext_vector_type(4))) float float4_t;

__device__ __forceinline__ short f2b(float f) {
    unsigned u = __builtin_bit_cast(unsigned, f);
    unsigned r = (u + 0x7FFFu + ((u >> 16) & 1u)) >> 16;
    return (short)(r & 0xFFFFu);
}

// ---------------- prep: x conversions (blocks 0..511) + weight transposes (blocks 512..591)
__global__ void prep(const float* __restrict__ qx, const float* __restrict__ kvx,
                     const float* __restrict__ Wq, const float* __restrict__ Wk,
                     const float* __restrict__ Wv, const float* __restrict__ Wg,
                     const float* __restrict__ Wo,
                     short* __restrict__ Xq, short* __restrict__ Xkv,
                     short* __restrict__ Wtbase) {
    __shared__ short S[64][72];
    int bid = blockIdx.x, tid = threadIdx.x;
    if (bid < 512) {
        int base = (bid * 256 + tid) * 8;
        const int NX = N_TOK * C_IN;
        const float* src; short* dst; int off;
        if (base < NX) { src = qx;  dst = Xq;  off = base; }
        else           { src = kvx; dst = Xkv; off = base - NX; }
        float4_t a = *(const float4_t*)(src + off);
        float4_t b = *(const float4_t*)(src + off + 4);
        short8 o;
        o[0] = f2b(a[0]); o[1] = f2b(a[1]); o[2] = f2b(a[2]); o[3] = f2b(a[3]);
        o[4] = f2b(b[0]); o[5] = f2b(b[1]); o[6] = f2b(b[2]); o[7] = f2b(b[3]);
        *(short8*)(dst + off) = o;
        return;
    }
    int b = bid - 512;
    int wi = b >> 4, t = b & 15;
    const float* W = (wi == 0) ? Wq : (wi == 1) ? Wk : (wi == 2) ? Wv : (wi == 3) ? Wg : Wo;
    short* Wt = Wtbase + wi * 65536;
    int r0 = (t >> 2) * 64, c0 = (t & 3) * 64;
    int tr = tid >> 4, tc = tid & 15;
#pragma unroll
    for (int i = 0; i < 4; i++) {
        int rr = tr + i * 16;
        float4_t v = *(const float4_t*)(W + (r0 + rr) * 256 + c0 + tc * 4);
        S[tc * 4 + 0][rr] = f2b(v[0]);
        S[tc * 4 + 1][rr] = f2b(v[1]);
        S[tc * 4 + 2][rr] = f2b(v[2]);
        S[tc * 4 + 3][rr] = f2b(v[3]);
    }
    __syncthreads();
    int cr = tid >> 3, co = (tid & 7) * 8;
#pragma unroll
    for (int i = 0; i < 2; i++) {
        int c = cr + i * 32;
        short8 v = *(const short8*)&S[c][co];
        *(short8*)(Wt + (c0 + c) * 256 + r0 + co) = v;
    }
}

// ---------------- fused projections: y=mode 0:q 1:k 2:gate 3:v ----------------
// wave computes a 16x16 output tile; grid (512, 4), 256 thr.
__global__ void proj(const short* __restrict__ Xq, const short* __restrict__ Xkv,
                     const short* __restrict__ Wtbase, const float* __restrict__ bg,
                     short* __restrict__ qh, short* __restrict__ kh,
                     short* __restrict__ vt, float* __restrict__ gsig) {
    int mode = blockIdx.y;
    int tid = threadIdx.x, wave = tid >> 6, lane = tid & 63, g16 = lane >> 4, li = lane & 15;
    const short* A;
    const short* B;
    int n0, c0;
    if (mode < 3) {
        A = (mode == 1) ? Xkv : Xq;
        B = Wtbase + (mode == 0 ? 0 : (mode == 1 ? 1 : 3)) * 65536;
        n0 = (blockIdx.x >> 2) * 16;                       // token rows
        c0 = ((blockIdx.x & 3) * 4 + wave) * 16;           // output channels
    } else {
        A = Wtbase + 2 * 65536;                            // Wtv rows = hd
        B = Xkv;                                           // cols = tokens
        n0 = (blockIdx.x >> 5) * 16;
        c0 = ((blockIdx.x & 31) * 4 + wave) * 16;
    }
    float4_t acc = (float4_t){0.f, 0.f, 0.f, 0.f};
    for (int k0 = 0; k0 < 256; k0 += 32) {
        short8 a = *(const short8*)(A + (n0 + li) * 256 + k0 + g16 * 8);
        short8 bfr = *(const short8*)(B + (c0 + li) * 256 + k0 + g16 * 8);
        acc = __builtin_amdgcn_mfma_f32_16x16x32_bf16(a, bfr, acc, 0, 0, 0);
    }
#pragma unroll
    for (int r = 0; r < 4; r++) {
        int row = n0 + g16 * 4 + r;
        int col = c0 + li;
        float v = acc[r];
        if (mode == 0) {
            qh[(col >> 5) * (N_TOK * DH) + row * DH + (col & 31)] =
                f2b(v * 0.17677669529663687f);
        } else if (mode == 1) {
            kh[(col >> 5) * (N_TOK * DH) + row * DH + (col & 31)] = f2b(v);
        } else if (mode == 2) {
            float x = v + bg[col];
            float e = __builtin_amdgcn_exp2f(-x * LOG2E);
            gsig[row * HDIM + col] = 1.f / (1.f + e);
        } else {
            vt[row * N_TOK + col] = f2b(v);  // row=hd, col=token
        }
    }
}

// ---------------- flash attention, in-block 8-way K-split ----------------
// grid (128 qtiles, 8 heads), 512 thr = 8 waves. Wave w: q rows [qt*16,+16),
// K range [w*256, w*256+256). LDS merge at end.
__global__ void __launch_bounds__(512, 4)
attn(const short* __restrict__ qh, const short* __restrict__ kh,
     const short* __restrict__ vt, const float* __restrict__ bias_mask,
     const float* __restrict__ bias_pair, const float* __restrict__ gsig,
     short* __restrict__ OG) {
    __shared__ short plds[8][16][72];
    __shared__ float po[8][16][33];
    __shared__ float pm[8][16];
    __shared__ float pl[8][16];
    int tid = threadIdx.x, wave = tid >> 6, lane = tid & 63, g16 = lane >> 4, li = lane & 15;
    int h = blockIdx.y, qt = blockIdx.x;
    int qbase = qt * 16;
    const short* qp = qh + h * (N_TOK * DH);
    const short* kp = kh + h * (N_TOK * DH);
    const short* vp = vt + h * (DH * N_TOK);
    short8 qa = *(const short8*)(qp + (qbase + li) * DH + g16 * 8);
    const float* bpp = bias_pair + ((size_t)h * N_TOK + qbase) * N_TOK;
    float m[4], l[4];
    float4_t o0 = {0.f, 0.f, 0.f, 0.f}, o1 = {0.f, 0.f, 0.f, 0.f};
#pragma unroll
    for (int r = 0; r < 4; r++) { m[r] = -1e30f; l[r] = 0.f; }
    const float4_t z4 = {0.f, 0.f, 0.f, 0.f};
    int kbeg = wave * 256;

#pragma unroll 1
    for (int kb = kbeg; kb < kbeg + 256; kb += 64) {
        float4_t s[4];
#pragma unroll
        for (int t = 0; t < 4; t++) {
            short8 kf = *(const short8*)(kp + (kb + t * 16 + li) * DH + g16 * 8);
            s[t] = __builtin_amdgcn_mfma_f32_16x16x32_bf16(qa, kf, z4, 0, 0, 0);
        }
        float bm[4];
#pragma unroll
        for (int t = 0; t < 4; t++) bm[t] = bias_mask[kb + t * 16 + li];
        float sc[4][4];
#pragma unroll
        for (int t = 0; t < 4; t++)
#pragma unroll
            for (int r = 0; r < 4; r++)
                sc[t][r] = s[t][r] + bm[t] + bpp[(g16 * 4 + r) * N_TOK + kb + t * 16 + li];

#pragma unroll
        for (int r = 0; r < 4; r++) {
            float mx = fmaxf(fmaxf(sc[0][r], sc[1][r]), fmaxf(sc[2][r], sc[3][r]));
#pragma unroll
            for (int off = 1; off < 16; off <<= 1) mx = fmaxf(mx, __shfl_xor(mx, off));
            float mn = fmaxf(m[r], mx);
            float sscale = __builtin_amdgcn_exp2f((m[r] - mn) * LOG2E);
            float su = 0.f;
#pragma unroll
            for (int t = 0; t < 4; t++) {
                float p = __builtin_amdgcn_exp2f((sc[t][r] - mn) * LOG2E);
                sc[t][r] = p;
                su += p;
            }
#pragma unroll
            for (int off = 1; off < 16; off <<= 1) su += __shfl_xor(su, off);
            l[r] = l[r] * sscale + su;
            m[r] = mn;
            o0[r] *= sscale;
            o1[r] *= sscale;
        }

#pragma unroll
        for (int t = 0; t < 4; t++)
#pragma unroll
            for (int r = 0; r < 4; r++)
                plds[wave][g16 * 4 + r][t * 16 + li] = f2b(sc[t][r]);
        short8 pa0 = *(const short8*)&plds[wave][li][g16 * 8];
        short8 pa1 = *(const short8*)&plds[wave][li][32 + g16 * 8];

        short8 v00 = *(const short8*)(vp + li * N_TOK + kb + g16 * 8);
        short8 v01 = *(const short8*)(vp + li * N_TOK + kb + 32 + g16 * 8);
        short8 v10 = *(const short8*)(vp + (16 + li) * N_TOK + kb + g16 * 8);
        short8 v11 = *(const short8*)(vp + (16 + li) * N_TOK + kb + 32 + g16 * 8);
        o0 = __builtin_amdgcn_mfma_f32_16x16x32_bf16(pa0, v00, o0, 0, 0, 0);
        o0 = __builtin_amdgcn_mfma_f32_16x16x32_bf16(pa1, v01, o0, 0, 0, 0);
        o1 = __builtin_amdgcn_mfma_f32_16x16x32_bf16(pa0, v10, o1, 0, 0, 0);
        o1 = __builtin_amdgcn_mfma_f32_16x16x32_bf16(pa1, v11, o1, 0, 0, 0);
    }

    // stash partials
#pragma unroll
    for (int r = 0; r < 4; r++) {
        po[wave][g16 * 4 + r][li] = o0[r];
        po[wave][g16 * 4 + r][16 + li] = o1[r];
    }
    if (li == 0) {
#pragma unroll
        for (int r = 0; r < 4; r++) {
            pm[wave][g16 * 4 + r] = m[r];
            pl[wave][g16 * 4 + r] = l[r];
        }
    }
    __syncthreads();

    // merge: one thread per (row, d); 16*32 = 512 threads
    int row = tid >> 5, d = tid & 31;
    float M = -1e30f;
#pragma unroll
    for (int w = 0; w < 8; w++) M = fmaxf(M, pm[w][row]);
    float L = 0.f, acc = 0.f;
#pragma unroll
    for (int w = 0; w < 8; w++) {
        float wt = __builtin_amdgcn_exp2f((pm[w][row] - M) * LOG2E);
        L += pl[w][row] * wt;
        acc += po[w][row][d] * wt;
    }
    int n = qbase + row;
    int col = h * DH + d;
    OG[n * HDIM + col] = f2b(acc / L * gsig[n * HDIM + col]);
}

// ---------------- output projection: wave = 16x16 tile, grid 512 ----------------
__global__ void outproj(const short* __restrict__ OG, const short* __restrict__ Wtbase,
                        const float* __restrict__ bo, float* __restrict__ out) {
    int tid = threadIdx.x, wave = tid >> 6, lane = tid & 63, g16 = lane >> 4, li = lane & 15;
    const short* Wto = Wtbase + 4 * 65536;
    int n0 = (blockIdx.x >> 2) * 16;
    int c0 = ((blockIdx.x & 3) * 4 + wave) * 16;
    float4_t acc = (float4_t){0.f, 0.f, 0.f, 0.f};
    for (int k0 = 0; k0 < HDIM; k0 += 32) {
        short8 a = *(const short8*)(OG + (n0 + li) * HDIM + k0 + g16 * 8);
        short8 b = *(const short8*)(Wto + (c0 + li) * HDIM + k0 + g16 * 8);
        acc = __builtin_amdgcn_mfma_f32_16x16x32_bf16(a, b, acc, 0, 0, 0);
    }
#pragma unroll
    for (int r = 0; r < 4; r++) {
        int n = n0 + g16 * 4 + r;
        int col = c0 + li;
        out[n * C_IN + col] = acc[r] + bo[col];
    }
}

extern "C" void kernel_launch(void* const* d_in, const int* in_sizes, int n_in,
                              void* d_out, int out_size, void* d_ws, size_t ws_size,
                              hipStream_t stream) {
    const float* q_x       = (const float*)d_in[0];
    const float* kv_x      = (const float*)d_in[1];
    const float* bias_mask = (const float*)d_in[2];
    const float* bias_pair = (const float*)d_in[3];
    const float* Wq        = (const float*)d_in[4];
    const float* Wk        = (const float*)d_in[5];
    const float* Wv        = (const float*)d_in[6];
    const float* Wo        = (const float*)d_in[7];
    const float* bo        = (const float*)d_in[8];
    const float* Wg        = (const float*)d_in[9];
    const float* bg        = (const float*)d_in[10];
    float* out = (float*)d_out;
    char* ws = (char*)d_ws;

    short* Xq     = (short*)(ws);                // 1 MB
    short* Xkv    = (short*)(ws + (1u << 20));   // 1 MB
    short* Wtbase = (short*)(ws + (2u << 20));   // 5 x 128 KB (q,k,v,g,o)
    short* qhb    = (short*)(ws + (3u << 20));   // 1 MB  [h][n][d] bf16
    short* khb    = (short*)(ws + (4u << 20));   // 1 MB
    short* vtb    = (short*)(ws + (5u << 20));   // 1 MB  [h][d][n] bf16
    float* gsig   = (float*)(ws + (6u << 20));   // 2 MB  [n][256] f32
    short* OG     = (short*)(ws + (8u << 20));   // 1 MB  [n][256] bf16

    hipLaunchKernelGGL(prep, dim3(592), dim3(256), 0, stream,
                       q_x, kv_x, Wq, Wk, Wv, Wg, Wo, Xq, Xkv, Wtbase);
    hipLaunchKernelGGL(proj, dim3(512, 4), dim3(256), 0, stream,
                       Xq, Xkv, Wtbase, bg, qhb, khb, vtb, gsig);
    hipLaunchKernelGGL(attn, dim3(128, 8), dim3(512), 0, stream,
                       qhb, khb, vtb, bias_mask, bias_pair, gsig, OG);
    hipLaunchKernelGGL(outproj, dim3(512), dim3(256), 0, stream, OG, Wtbase, bo, out);
}